// Round 7
// baseline (1784.870 us; speedup 1.0000x reference)
//
#include <hip/hip_runtime.h>
#include <math.h>

#define NB    8
#define NE    1024
#define DDIM  256
#define TTOK  4096
#define BBATCH 16
#define NTOK  (BBATCH*TTOK)   // 65536

#define TM    64      // tokens per block
#define RSTR  260     // res_s row stride (floats), 16B aligned
#define EPS_GAP 1e-4f // certify threshold: approx top-2 gap below this -> exact rescore

typedef _Float16 half8 __attribute__((ext_vector_type(8)));
typedef float f32x4 __attribute__((ext_vector_type(4)));

#define MFMA16(A,B,C) __builtin_amdgcn_mfma_f32_16x16x32_f16(A,B,C,0,0,0)

// ---------- h[c] = 0.5*sum(e*e) with numpy pairwise-sum semantics (unchanged) ----------
__global__ void hsum_kernel(const float* __restrict__ books, float* __restrict__ hg) {
    int c = blockIdx.x * blockDim.x + threadIdx.x;
    if (c >= NB * NE) return;
    const float* e = books + (size_t)c * DDIM;
    float blk[2];
    for (int half = 0; half < 2; ++half) {
        const float* a = e + half * 128;
        float r[8];
        #pragma unroll
        for (int j = 0; j < 8; ++j) {
            float s = a[j] * a[j];
            asm volatile("" : "+v"(s));
            r[j] = s;
        }
        for (int i = 8; i < 128; i += 8) {
            #pragma unroll
            for (int j = 0; j < 8; ++j) {
                float s = a[i + j] * a[i + j];
                asm volatile("" : "+v"(s));
                r[j] = r[j] + s;
            }
        }
        blk[half] = ((r[0] + r[1]) + (r[2] + r[3])) + ((r[4] + r[5]) + (r[6] + r[7]));
    }
    hg[c] = 0.5f * (blk[0] + blk[1]);
}

// ---------- z (B,D,T) -> zt[token][dim] (unchanged) ----------
__global__ void txin_kernel(const float* __restrict__ z, float* __restrict__ zt) {
    __shared__ float ld[64 * 68];
    int t0 = blockIdx.x * 64, d0 = blockIdx.y * 64, b = blockIdx.z;
    int tid = threadIdx.x;
    {
        int dd = tid >> 2, t4 = (tid & 3) * 16;
        const float* zp = z + ((size_t)b * DDIM + d0 + dd) * TTOK + t0 + t4;
        #pragma unroll
        for (int c = 0; c < 16; c += 4)
            *(float4*)&ld[dd * 68 + t4 + c] = *(const float4*)(zp + c);
    }
    __syncthreads();
    {
        int t = tid >> 2, d4 = (tid & 3) * 16;
        float* rp = zt + ((size_t)b * TTOK + t0 + t) * DDIM + d0 + d4;
        #pragma unroll
        for (int c = 0; c < 16; c += 4) {
            float4 o;
            o.x = ld[(size_t)(d4 + c + 0) * 68 + t];
            o.y = ld[(size_t)(d4 + c + 1) * 68 + t];
            o.z = ld[(size_t)(d4 + c + 2) * 68 + t];
            o.w = ld[(size_t)(d4 + c + 3) * 68 + t];
            *(float4*)(rp + c) = o;
        }
    }
}

// ---------- books -> stream-ordered packed MFMA-B fragments ----------
// Layout: [cq 4][b 8][cc 8][s 8] packets of 4KB; packet = {f0 hi 1KB, f0 lo 1KB,
// f1 hi 1KB, f1 lo 1KB} where f0/f1 = code-frags F = cq*16 + cc*2 + {0,1}.
// Within a 1KB piece: lane l elem j holds code n = F*16 + (l&15),
// k = s*32 + (l>>4)*8 + j (v_mfma_f32_16x16x32_f16 B layout).
// Per code-quarter the walk over (b, cc, s) is ONE linear 2MB stream.
__global__ void bfrag_kernel(const float* __restrict__ books,
                             _Float16* __restrict__ Bp) {
    const int gid = blockIdx.x * 256 + threadIdx.x;   // 262144 total
    const int l = gid & 63;
    const int s = (gid >> 6) & 7;
    const int F = (gid >> 9) & 63;
    const int b = gid >> 15;
    const int cq = F >> 4, cc = (F >> 1) & 7, pr = F & 1;
    const int n = F * 16 + (l & 15);
    const int k0 = s * 32 + (l >> 4) * 8;
    const float* src = books + ((size_t)b * NE + n) * DDIM + k0;
    float4 xa = *(const float4*)src;
    float4 xb = *(const float4*)(src + 4);
    float xs[8] = {xa.x, xa.y, xa.z, xa.w, xb.x, xb.y, xb.z, xb.w};
    half8 vh, vl;
    #pragma unroll
    for (int j = 0; j < 8; ++j) {
        float x = xs[j];
        _Float16 hx = (_Float16)x;
        float hf = (float)hx;
        // flush denormal hi at split time so MFMA's view == our compensated view
        if (__builtin_fabsf(hf) < 6.103515625e-05f) { hx = (_Float16)0.f; hf = 0.f; }
        vh[j] = hx;
        vl[j] = (_Float16)((x - hf) * 4096.f);   // x-hf exact (Sterbenz), *2^12 exact
    }
    const size_t pkt = (((size_t)cq * 8 + b) * 8 + cc) * 8 + s;
    const size_t o = pkt * 2048 + (size_t)pr * 1024 + (size_t)l * 8;
    *(half8*)(Bp + o) = vh;
    *(half8*)(Bp + o + 512) = vl;
}

// One inner k-step. Slot regs (QH0,QL0,QH1,QL1) were loaded 2 steps ago:
// wait vmcnt(4) = allow the 1-step-old refill (4 loads) in flight, require ours
// done. sched_barrier(0) right after (rule #18) stops MFMA hoisting above the
// wait. A-reads are compiler ds_read (it emits its own lgkmcnt). Refill of this
// slot (packet s+2) is issued AFTER the MFMAs consume the old values; asm
// volatile program order keeps the queue discipline the RA-friendly way (R5/R6
// lesson: this is what keeps VGPR<=128 with zero scratch).
#define VQ_STEP(QH0, QL0, QH1, QL1, S) do {                                   \
    asm volatile("s_waitcnt vmcnt(4)");                                       \
    __builtin_amdgcn_sched_barrier(0);                                        \
    half8 ah0 = *(const half8*)&RHs[(a0 + (S)) * 520 + (lane << 3)];          \
    half8 al0 = *(const half8*)&RLs[(a0 + (S)) * 520 + (lane << 3)];          \
    half8 ah1 = *(const half8*)&RHs[(a1 + (S)) * 520 + (lane << 3)];          \
    half8 al1 = *(const half8*)&RLs[(a1 + (S)) * 520 + (lane << 3)];          \
    acch[0] = MFMA16(ah0, QH0, acch[0]);                                      \
    accm[0] = MFMA16(ah0, QL0, accm[0]);                                      \
    accm[0] = MFMA16(al0, QH0, accm[0]);                                      \
    acch[1] = MFMA16(ah1, QH0, acch[1]);                                      \
    accm[1] = MFMA16(ah1, QL0, accm[1]);                                      \
    accm[1] = MFMA16(al1, QH0, accm[1]);                                      \
    acch[2] = MFMA16(ah0, QH1, acch[2]);                                      \
    accm[2] = MFMA16(ah0, QL1, accm[2]);                                      \
    accm[2] = MFMA16(al0, QH1, accm[2]);                                      \
    acch[3] = MFMA16(ah1, QH1, acch[3]);                                      \
    accm[3] = MFMA16(ah1, QL1, accm[3]);                                      \
    accm[3] = MFMA16(al1, QH1, accm[3]);                                      \
    asm volatile("global_load_dwordx4 %0, %4, off\n\t"                        \
                 "global_load_dwordx4 %1, %4, off offset:1024\n\t"            \
                 "global_load_dwordx4 %2, %4, off offset:2048\n\t"            \
                 "global_load_dwordx4 %3, %4, off offset:3072"                \
                 : "=&v"(QH0), "=&v"(QL0), "=&v"(QH1), "=&v"(QL1)             \
                 : "v"(sp));                                                  \
    sp += 2048;                                                               \
} while (0)

// ---------- main scan: split-fp16 MFMA scores + EPS-certified exact fallback ----------
// 512 threads = 8 waves. Wave w owns token-half th=w&1 (32 tokens, m-frags 2th/2th+1)
// and code-quarter cq=w>>1 (256 codes). R6 lesson: compiler waitcnt around the
// sched_barrier'd loop was vmcnt(0)-conservative -> ~1830 cyc/step of exposed
// latency. Here ALL steady-loop B loads are inline asm with hand-counted
// vmcnt(4): compiler tracks no VMEM in the loop and inserts no waits. A raw
// s_barrier per cc-chunk paces the two th-waves (same CU) within 32KB of each
// other so the partner's identical loads hit L1 -> L2/L3 demand halves.
__launch_bounds__(512)
__global__ void vq_main(const float* __restrict__ books,
                        const _Float16* __restrict__ Bp,
                        const float* __restrict__ hg,
                        const float* __restrict__ zt,
                        int* __restrict__ idxg) {
    __shared__ float res_s[TM * RSTR];          // 66,560 B exact fp32 residual
    __shared__ _Float16 RHs[32 * 520];          // 33,280 B residual hi fragments
    __shared__ _Float16 RLs[32 * 520];          // 33,280 B residual lo fragments
    __shared__ float h_s[NE];                   // 4 KB per-book h
    __shared__ float cand_v1[4 * TM];
    __shared__ float cand_v2[4 * TM];
    __shared__ int   cand_n[4 * TM];
    __shared__ int   bidx_s[TM];
    __shared__ int   flist[TM];
    __shared__ int   nflag;

    const int tid  = threadIdx.x;
    const int lane = tid & 63;
    const int w    = tid >> 6;
    const int th   = w & 1;        // token half (m-frags 2th, 2th+1)
    const int cq   = w >> 1;       // code quarter (codes cq*256..cq*256+255)
    const int g    = lane >> 4;    // C-row group
    const int cl   = lane & 15;    // C-col within fragment
    const size_t tok0 = (size_t)blockIdx.x * TM;

    { // stage residual = z tokens into LDS
        int m = tid >> 3, qc = (tid & 7) * 32;
        const float* zp = zt + (tok0 + m) * DDIM + qc;
        float* rp = &res_s[m * RSTR + qc];
        #pragma unroll
        for (int c = 0; c < 32; c += 4)
            *(float4*)(rp + c) = *(const float4*)(zp + c);
    }

    // ---- B stream: asm prologue-fill of the 2-deep named-slot queue ----
    const _Float16* sp = Bp + ((size_t)cq << 20) + (size_t)(lane << 3);
    half8 qXh0, qXl0, qXh1, qXl1, qYh0, qYl0, qYh1, qYl1;
    asm volatile("global_load_dwordx4 %0, %4, off\n\t"
                 "global_load_dwordx4 %1, %4, off offset:1024\n\t"
                 "global_load_dwordx4 %2, %4, off offset:2048\n\t"
                 "global_load_dwordx4 %3, %4, off offset:3072"
                 : "=&v"(qXh0), "=&v"(qXl0), "=&v"(qXh1), "=&v"(qXl1)
                 : "v"(sp));
    sp += 2048;
    asm volatile("global_load_dwordx4 %0, %4, off\n\t"
                 "global_load_dwordx4 %1, %4, off offset:1024\n\t"
                 "global_load_dwordx4 %2, %4, off offset:2048\n\t"
                 "global_load_dwordx4 %3, %4, off offset:3072"
                 : "=&v"(qYh0), "=&v"(qYl0), "=&v"(qYh1), "=&v"(qYl1)
                 : "v"(sp));
    sp += 2048;

    const int fi = tid >> 4;       // fragment id 0..31 = m*8 + s (split phase)
    const int fp = tid & 15;       // 1/16 of a fragment
    const int a0 = (th * 2) * 8;   // m-frag 0 row base in RHs/RLs
    const int a1 = (th * 2 + 1) * 8;

    for (int b = 0; b < NB; ++b) {
        __syncthreads();           // res_s ready (initial stage or prev update)
        for (int i = tid; i < NE; i += 512) h_s[i] = hg[b * NE + i];
        if (tid == 0) nflag = 0;
        { // split residual -> fragment-ordered fp16 hi/lo (A layout: row=l&15, k=(l>>4)*8+j)
            const int sm = fi >> 3, ss = fi & 7;
            #pragma unroll
            for (int c = 0; c < 4; ++c) {
                int lp = fp * 4 + c;
                const float* rp = &res_s[(sm * 16 + (lp & 15)) * RSTR + ss * 32 + (lp >> 4) * 8];
                float4 xa = *(const float4*)rp;
                float4 xb = *(const float4*)(rp + 4);
                float xs[8] = {xa.x, xa.y, xa.z, xa.w, xb.x, xb.y, xb.z, xb.w};
                half8 vh, vl;
                #pragma unroll
                for (int j = 0; j < 8; ++j) {
                    float x = xs[j];
                    _Float16 hx = (_Float16)x;
                    float hf = (float)hx;
                    if (__builtin_fabsf(hf) < 6.103515625e-05f) { hx = (_Float16)0.f; hf = 0.f; }
                    vh[j] = hx;
                    vl[j] = (_Float16)((x - hf) * 4096.f);
                }
                *(half8*)&RHs[fi * 520 + fp * 32 + c * 8] = vh;
                *(half8*)&RLs[fi * 520 + fp * 32 + c * 8] = vl;
            }
        }
        __syncthreads();

        // per-lane running top-2 for 8 token slots (slot mfl*4+r -> token th*32+mfl*16+g*4+r)
        float v1[8], v2[8];
        unsigned bc = 0;           // 4-bit best chunk-frag (cc*2+f) per slot
        #pragma unroll
        for (int r = 0; r < 8; ++r) { v1[r] = -3.4e38f; v2[r] = -3.4e38f; }

        const f32x4 fz = {0.f, 0.f, 0.f, 0.f};
        for (int cc = 0; cc < 8; ++cc) {         // 8 chunks of 2 frags (32 codes)
            f32x4 acch[4], accm[4];              // [f*2+mfl]: hi*hi and mixed(x4096)
            #pragma unroll
            for (int m = 0; m < 4; ++m) { acch[m] = fz; accm[m] = fz; }

            #pragma unroll
            for (int s2 = 0; s2 < 4; ++s2) {     // K = 8 * 32, two slots per iter
                VQ_STEP(qXh0, qXl0, qXh1, qXl1, s2 * 2);
                VQ_STEP(qYh0, qYl0, qYh1, qYl1, s2 * 2 + 1);
            }
            // fold: codes ascending (cc asc, f asc) -> strict '>' keeps first max
            #pragma unroll
            for (int f = 0; f < 2; ++f) {
                const int cf = cc * 2 + f;
                const int n = (cq << 8) + (cf << 4) + cl;
                const float hv = h_s[n];
                #pragma unroll
                for (int mfl = 0; mfl < 2; ++mfl)
                    #pragma unroll
                    for (int r = 0; r < 4; ++r) {
                        float sc = acch[f * 2 + mfl][r] + 2.44140625e-4f * accm[f * 2 + mfl][r] - hv;
                        const int sl = mfl * 4 + r;
                        if (sc > v1[sl]) {
                            v2[sl] = v1[sl]; v1[sl] = sc;
                            bc = (bc & ~(15u << (4 * sl))) | ((unsigned)cf << (4 * sl));
                        } else v2[sl] = fmaxf(v2[sl], sc);
                    }
            }
            // pacing barrier (raw, no memory drain): keeps the two th-waves of a
            // cq stream <=1 chunk apart so partner loads hit L1/L2, not L3.
            __builtin_amdgcn_s_barrier();
        }
        // reconstruct best-code indices, then reduce top-2 across the 16 lanes
        int n1[8];
        #pragma unroll
        for (int sl = 0; sl < 8; ++sl)
            n1[sl] = (cq << 8) + ((int)((bc >> (4 * sl)) & 15u) << 4) + cl;
        #pragma unroll
        for (int sl = 0; sl < 8; ++sl) {
            #pragma unroll
            for (int mk = 1; mk < 16; mk <<= 1) {
                float o1 = __shfl_xor(v1[sl], mk, 16);
                float o2 = __shfl_xor(v2[sl], mk, 16);
                int   on = __shfl_xor(n1[sl], mk, 16);
                if (o1 > v1[sl] || (o1 == v1[sl] && on < n1[sl])) {
                    v2[sl] = fmaxf(v1[sl], o2);
                    v1[sl] = o1; n1[sl] = on;
                } else {
                    v2[sl] = fmaxf(v2[sl], o1);
                }
            }
        }
        if (cl == 0) {
            #pragma unroll
            for (int sl = 0; sl < 8; ++sl) {
                int t = th * 32 + (sl >> 2) * 16 + g * 4 + (sl & 3);
                cand_v1[cq * TM + t] = v1[sl];
                cand_v2[cq * TM + t] = v2[sl];
                cand_n [cq * TM + t] = n1[sl];
            }
        }
        __syncthreads();
        // combine the four code-quarters (ascending); flag near-ties for exact rescore
        if (tid < TM) {
            float b1v = cand_v1[tid], b2v = cand_v2[tid]; int bn = cand_n[tid];
            #pragma unroll
            for (int ww = 1; ww < 4; ++ww) {
                float o1 = cand_v1[ww * TM + tid], o2 = cand_v2[ww * TM + tid];
                int   on = cand_n[ww * TM + tid];
                if (o1 > b1v) { b2v = fmaxf(b1v, o2); b1v = o1; bn = on; }
                else b2v = fmaxf(b2v, o1);   // ties (o1==b1v) drive gap to 0 -> flagged
            }
            bidx_s[tid] = bn;
            if (b1v - b2v < EPS_GAP) { int p2 = atomicAdd(&nflag, 1); flist[p2] = tid; }
        }
        __syncthreads();
        // exact fp32 rescore (validated numerics: k-ascending single-acc fmaf chain)
        {
            const int nfl = nflag;
            for (int f = w; f < nfl; f += 8) {
                const int t = flist[f];
                const float* rrow = &res_s[t * RSTR];
                float best = -3.4e38f; int bestn = 0;
                for (int i = 0; i < 16; ++i) {
                    const int n = lane + (i << 6);
                    const float* crow = books + ((size_t)b * NE + n) * DDIM;
                    float acc = 0.f;
                    #pragma unroll 4
                    for (int k = 0; k < DDIM; k += 4) {
                        float4 rv = *(const float4*)(rrow + k);
                        float4 cv = *(const float4*)(crow + k);
                        acc = __builtin_fmaf(rv.x, cv.x, acc);
                        acc = __builtin_fmaf(rv.y, cv.y, acc);
                        acc = __builtin_fmaf(rv.z, cv.z, acc);
                        acc = __builtin_fmaf(rv.w, cv.w, acc);
                    }
                    float sc = acc - h_s[n];
                    if (sc > best) { best = sc; bestn = n; }
                }
                #pragma unroll
                for (int mk = 32; mk; mk >>= 1) {
                    float ov = __shfl_xor(best, mk, 64);
                    int   on = __shfl_xor(bestn, mk, 64);
                    if (ov > best || (ov == best && on < bestn)) { best = ov; bestn = on; }
                }
                if (lane == 0) bidx_s[t] = bestn;
            }
        }
        __syncthreads();
        if (tid < TM) idxg[(tok0 + tid) * NB + b] = bidx_s[tid];
        { // residual update r = r - q (plain fp32 subs, matches reference chain)
            int m = tid >> 3, qc = (tid & 7) * 32;
            const float* qrow = books + ((size_t)b * NE + bidx_s[m]) * DDIM + qc;
            float* rrow = &res_s[m * RSTR + qc];
            #pragma unroll
            for (int c2 = 0; c2 < 32; c2 += 4) {
                float4 qv = *(const float4*)(qrow + c2);
                float4 rv2 = *(float4*)(rrow + c2);
                rv2.x = rv2.x - qv.x; rv2.y = rv2.y - qv.y;
                rv2.z = rv2.z - qv.z; rv2.w = rv2.w - qv.w;
                *(float4*)(rrow + c2) = rv2;
            }
        }
    }
}

// ---------- replay: q_sum with the reference's exact fp32 op order (unchanged) ----------
__global__ void replay_kernel(const float* __restrict__ books,
                              const int* __restrict__ idxg,
                              float* __restrict__ zt) {
    size_t gid = (size_t)blockIdx.x * 256 + threadIdx.x;
    size_t tok = gid >> 6;
    int d4 = (int)(gid & 63) * 4;
    const int* ip = idxg + tok * NB;
    float4 r = *(const float4*)&zt[tok * DDIM + d4];
    float4 qs = make_float4(0.f, 0.f, 0.f, 0.f);
    #pragma unroll
    for (int b = 0; b < NB; ++b) {
        int idx = ip[b];
        float4 q = *(const float4*)&books[((size_t)b * NE + idx) * DDIM + d4];
        float t1;
        t1 = q.x - r.x; qs.x = qs.x + t1; qs.x = qs.x + r.x; r.x = r.x - q.x;
        t1 = q.y - r.y; qs.y = qs.y + t1; qs.y = qs.y + r.y; r.y = r.y - q.y;
        t1 = q.z - r.z; qs.z = qs.z + t1; qs.z = qs.z + r.z; r.z = r.z - q.z;
        t1 = q.w - r.w; qs.w = qs.w + t1; qs.w = qs.w + r.w; r.w = r.w - q.w;
    }
    *(float4*)&zt[tok * DDIM + d4] = qs;
}

// ---------- out (B,D,T) = transpose of q_sum[token][dim] (unchanged) ----------
__global__ void fin_kernel(const float* __restrict__ qst, float* __restrict__ out) {
    __shared__ float ld[64 * 68];
    int t0 = blockIdx.x * 64, d0 = blockIdx.y * 64, b = blockIdx.z;
    int tid = threadIdx.x;
    {
        int t = tid >> 2, d4 = (tid & 3) * 16;
        const float* rp = qst + ((size_t)b * TTOK + t0 + t) * DDIM + d0 + d4;
        #pragma unroll
        for (int c = 0; c < 16; c += 4)
            *(float4*)&ld[t * 68 + d4 + c] = *(const float4*)(rp + c);
    }
    __syncthreads();
    {
        int dd = tid >> 2, t4 = (tid & 3) * 16;
        float* op = out + ((size_t)b * DDIM + d0 + dd) * TTOK + t0 + t4;
        #pragma unroll
        for (int c = 0; c < 16; c += 4) {
            float4 o;
            o.x = ld[(size_t)(t4 + c + 0) * 68 + dd];
            o.y = ld[(size_t)(t4 + c + 1) * 68 + dd];
            o.z = ld[(size_t)(t4 + c + 2) * 68 + dd];
            o.w = ld[(size_t)(t4 + c + 3) * 68 + dd];
            *(float4*)(op + c) = o;
        }
    }
}

extern "C" void kernel_launch(void* const* d_in, const int* in_sizes, int n_in,
                              void* d_out, int out_size, void* d_ws, size_t ws_size,
                              hipStream_t stream) {
    const float* z     = (const float*)d_in[0];
    const float* books = (const float*)d_in[1];
    float* out = (float*)d_out;

    float* hg    = (float*)d_ws;                         // 8192 floats
    int*   idxg  = (int*)(hg + (size_t)NB * NE);         // 65536*8 ints (2 MB)
    _Float16* Bp = (_Float16*)(idxg + (size_t)NTOK * NB);// 8 MB stream-ordered fragments
    float* zt    = (float*)(Bp + (size_t)NB * NE * DDIM * 2); // 64 MB token-major
    // NOTE: vq_main's rolling 2-deep prefetch reads <=8KB past Bp's end -> zt, discarded.

    hsum_kernel<<<(NB * NE + 255) / 256, 256, 0, stream>>>(books, hg);
    bfrag_kernel<<<(NB * 64 * 8 * 64) / 256, 256, 0, stream>>>(books, Bp);
    txin_kernel<<<dim3(TTOK / 64, DDIM / 64, BBATCH), 256, 0, stream>>>(z, zt);
    vq_main<<<NTOK / TM, 512, 0, stream>>>(books, Bp, hg, zt, idxg);
    replay_kernel<<<NTOK * 64 / 256, 256, 0, stream>>>(books, idxg, zt);
    fin_kernel<<<dim3(TTOK / 64, DDIM / 64, BBATCH), 256, 0, stream>>>(zt, out);
}